// Round 16
// baseline (473.211 us; speedup 1.0000x reference)
//
#include <hip/hip_runtime.h>

#define NN   50000
#define IN_F 128
#define HF   256
#define COUT 64
#define MLPH 128
#define EG   600000
#define EK   800000
#define RNG  6250    // NN / 8
#define SUBR 782     // ceil(RNG / 8)
#define CAPG 80000
#define CAPK 106000
#define BN_EPS 1e-5f

typedef __attribute__((ext_vector_type(8))) short short8;
typedef __attribute__((ext_vector_type(8))) unsigned short ushort8;
typedef __attribute__((ext_vector_type(4))) float f32x4;

__device__ __forceinline__ unsigned short f2bf(float f) {
  union { float f; unsigned int u; } v; v.f = f;
  unsigned int r = v.u + 0x7FFFu + ((v.u >> 16) & 1u);
  return (unsigned short)(r >> 16);
}
__device__ __forceinline__ float bf2f(unsigned short s) {
  union { unsigned int u; float f; } v; v.u = ((unsigned int)s) << 16;
  return v.f;
}

__device__ __forceinline__ void gload_lds16(const void* g, void* l) {
  __builtin_amdgcn_global_load_lds((const __attribute__((address_space(1))) void*)g,
                                   (__attribute__((address_space(3))) void*)l, 16, 0, 0);
}

struct WDesc { const float* src; int rows; int cshift; int kofs; int ldk; int dofs; };
struct WPack { WDesc d[12]; };

// ---------------- prep: feat->bf16, weight transpose ----------------
__global__ __launch_bounds__(256) void prep_kernel(const float* __restrict__ feat,
                                                   unsigned short* __restrict__ featbf,
                                                   WPack p, unsigned short* __restrict__ wts) {
  int b = blockIdx.x;
  if (b < 3126) {
    int i = b * 256 + threadIdx.x;
    if (i < NN * IN_F / 8) {
      float4 a = *reinterpret_cast<const float4*>(&feat[i * 8]);
      float4 c = *reinterpret_cast<const float4*>(&feat[i * 8 + 4]);
      ushort8 o;
      o[0] = f2bf(a.x); o[1] = f2bf(a.y); o[2] = f2bf(a.z); o[3] = f2bf(a.w);
      o[4] = f2bf(c.x); o[5] = f2bf(c.y); o[6] = f2bf(c.z); o[7] = f2bf(c.w);
      *reinterpret_cast<ushort8*>(&featbf[i * 8]) = o;
    }
  } else {
    int wb = b - 3126;
    WDesc w = p.d[wb >> 5];
    int xb = wb & 31;
    int total = w.rows << w.cshift;
    int cmask = (1 << w.cshift) - 1;
    for (int idx = xb * 256 + threadIdx.x; idx < total; idx += 32 * 256) {
      int r = idx >> w.cshift, c = idx & cmask;
      wts[w.dofs + (size_t)c * w.ldk + w.kofs + r] = f2bf(w.src[idx]);
    }
  }
}

// ---------------- fused head weights ----------------
__global__ __launch_bounds__(128) void fuse_w_kernel(
    const float* __restrict__ wl2s, const float* __restrict__ wl2n,
    const float* __restrict__ wg1s, const float* __restrict__ wg1n,
    const float* __restrict__ w1, const float* __restrict__ bl2,
    const float* __restrict__ bg1, const float* __restrict__ b1,
    unsigned short* __restrict__ wf, float* __restrict__ bfused) {
  int b = blockIdx.x;
  int c = threadIdx.x;
  __shared__ float row[256];
  if (b < 1024) {
    int seg = b >> 8, i = b & 255;
    const float* W = (seg == 0) ? wl2s : (seg == 1) ? wl2n : (seg == 2) ? wg1s : wg1n;
    const float* w1b = w1 + ((seg < 2) ? 0 : 256) * MLPH;
    row[c] = W[i * 256 + c];
    row[c + 128] = W[i * 256 + 128 + c];
    __syncthreads();
    float acc = 0.f;
    for (int o = 0; o < 256; ++o) acc += row[o] * w1b[o * MLPH + c];
    unsigned short v = f2bf(acc);
    if (seg == 0)      wf[(size_t)c * 512 + i] = v;
    else if (seg == 2) wf[(size_t)c * 512 + 256 + i] = v;
    else if (seg == 1) wf[65536 + (size_t)c * 256 + i] = v;
    else               wf[98304 + (size_t)c * 256 + i] = v;
  } else {
    float acc = b1[c];
    for (int o = 0; o < 256; ++o) acc += bl2[o] * w1[o * MLPH + c];
    for (int o = 0; o < 256; ++o) acc += bg1[o] * w1[(256 + o) * MLPH + c];
    bfused[c] = acc;
  }
}

// ---------------- edge bucketing ----------------
__global__ __launch_bounds__(256) void bucket_kernel(const int* __restrict__ g_src,
                                                     const int* __restrict__ g_dst,
                                                     const int* __restrict__ k_src,
                                                     const int* __restrict__ k_dst,
                                                     int* __restrict__ gcnt,
                                                     unsigned* __restrict__ bkt_g,
                                                     unsigned* __restrict__ bkt_k) {
  __shared__ unsigned buf[2048];
  __shared__ int rcnt[8], rbase[8], roff[8];
  const int gr = blockIdx.y;
  const int* src = gr ? k_src : g_src;
  const int* dst = gr ? k_dst : g_dst;
  unsigned* bkt = gr ? bkt_k : bkt_g;
  const int CAP = gr ? CAPK : CAPG;
  const int E = gr ? EK : EG;
  int* gc = gcnt + gr * 8;
  const int tid = threadIdx.x;
  const int e0 = blockIdx.x * 2048;
  if (e0 >= E) return;
  if (tid < 8) rcnt[tid] = 0;
  __syncthreads();
  unsigned vloc[8];
  int rloc[8], ploc[8];
#pragma unroll
  for (int i = 0; i < 8; ++i) {
    int e = e0 + i * 256 + tid;
    rloc[i] = -1;
    if (e < E) {
      int d = dst[e], s = src[e];
      int r = d / RNG;
      vloc[i] = ((unsigned)d << 16) | (unsigned)s;
      rloc[i] = r;
      ploc[i] = atomicAdd(&rcnt[r], 1);
    }
  }
  __syncthreads();
  if (tid == 0) {
    int acc = 0;
#pragma unroll
    for (int r = 0; r < 8; ++r) { roff[r] = acc; acc += rcnt[r]; }
  }
  __syncthreads();
#pragma unroll
  for (int i = 0; i < 8; ++i)
    if (rloc[i] >= 0) buf[roff[rloc[i]] + ploc[i]] = vloc[i];
  __syncthreads();
  if (tid < 8) rbase[tid] = atomicAdd(&gc[tid], rcnt[tid]);
  __syncthreads();
#pragma unroll
  for (int r = 0; r < 8; ++r) {
    int len = rcnt[r];
    unsigned* dstp = bkt + (size_t)r * CAP + rbase[r];
    for (int i = tid; i < len; i += 256) dstp[i] = buf[roff[r] + i];
  }
}

// ---------------- per-range count (LDS histogram) ----------------
__global__ __launch_bounds__(256) void count_bucket(const unsigned* __restrict__ bkt_g,
                                                    const unsigned* __restrict__ bkt_k,
                                                    const int* __restrict__ gcnt,
                                                    int* __restrict__ cnt_g,
                                                    int* __restrict__ cnt_k, int CC) {
  __shared__ int hist[RNG];
  const int r = blockIdx.x, gr = blockIdx.y, z = blockIdx.z;
  const unsigned* b = (gr ? bkt_k : bkt_g) + (size_t)r * (gr ? CAPK : CAPG);
  int* cnt = gr ? cnt_k : cnt_g;
  const int n = gcnt[gr * 8 + r];
  const unsigned lo = r * RNG;
  for (int i = threadIdx.x; i < RNG; i += 256) hist[i] = 0;
  __syncthreads();
  for (int i = z * 256 + threadIdx.x; i < n; i += CC * 256) {
    unsigned d = (b[i] >> 16) - lo;
    atomicAdd(&hist[d], 1);
  }
  __syncthreads();
  for (int i = threadIdx.x; i < RNG; i += 256) {
    int v = hist[i];
    if (v) atomicAdd(&cnt[lo + i], v);
  }
}

// ---------------- parallel scans ----------------
__global__ __launch_bounds__(256) void scan_partial2(const int* __restrict__ cnt_g,
                                                     const int* __restrict__ cnt_k,
                                                     int* __restrict__ part, int n) {
  const int* cnt = blockIdx.y ? cnt_k : cnt_g;
  int* pp = part + blockIdx.y * 256;
  int i = blockIdx.x * 256 + threadIdx.x;
  int v = (i < n) ? cnt[i] : 0;
  __shared__ int ws[4];
  int lane = threadIdx.x & 63, wid = threadIdx.x >> 6;
  int x = v;
#pragma unroll
  for (int d = 1; d < 64; d <<= 1) { int y = __shfl_up(x, d, 64); if (lane >= d) x += y; }
  if (lane == 63) ws[wid] = x;
  __syncthreads();
  if (threadIdx.x == 0) pp[blockIdx.x] = ws[0] + ws[1] + ws[2] + ws[3];
}

__global__ __launch_bounds__(256) void scan_block2(int* __restrict__ part, int np) {
  int* pp = part + blockIdx.x * 256;
  __shared__ int ws[4];
  int tid = threadIdx.x, lane = tid & 63, wid = tid >> 6;
  int v = (tid < np) ? pp[tid] : 0;
  int x = v;
#pragma unroll
  for (int d = 1; d < 64; d <<= 1) { int y = __shfl_up(x, d, 64); if (lane >= d) x += y; }
  if (lane == 63) ws[wid] = x;
  __syncthreads();
  int add = 0;
#pragma unroll
  for (int k = 0; k < 4; ++k) if (k < wid) add += ws[k];
  if (tid < np) pp[tid] = x - v + add;
}

__global__ __launch_bounds__(256) void scan_final2(const int* __restrict__ cnt_g,
                                                   const int* __restrict__ cnt_k,
                                                   const int* __restrict__ part,
                                                   int* __restrict__ off_g,
                                                   int* __restrict__ off_k,
                                                   float* __restrict__ invg,
                                                   float* __restrict__ invk, int n) {
  const int* cnt = blockIdx.y ? cnt_k : cnt_g;
  const int* pp = part + blockIdx.y * 256;
  int* off = blockIdx.y ? off_k : off_g;
  float* inv = blockIdx.y ? invk : invg;
  int total = blockIdx.y ? EK : EG;
  int i = blockIdx.x * 256 + threadIdx.x;
  int v = (i < n) ? cnt[i] : 0;
  __shared__ int ws[4];
  int lane = threadIdx.x & 63, wid = threadIdx.x >> 6;
  int x = v;
#pragma unroll
  for (int d = 1; d < 64; d <<= 1) { int y = __shfl_up(x, d, 64); if (lane >= d) x += y; }
  if (lane == 63) ws[wid] = x;
  __syncthreads();
  int add = pp[blockIdx.x];
#pragma unroll
  for (int k = 0; k < 4; ++k) if (k < wid) add += ws[k];
  if (i < n) {
    off[i] = x - v + add;
    inv[i] = 1.0f / fmaxf((float)v, 1.0f);
  }
  if (i == 0) off[n] = total;
}

// ---------------- CSR fill: 8 sub-ranges, LDS cursors ----------------
__global__ __launch_bounds__(1024) void fill_sub(const unsigned* __restrict__ bkt_g,
                                                 const unsigned* __restrict__ bkt_k,
                                                 const int* __restrict__ gcnt,
                                                 const int* __restrict__ off_g,
                                                 const int* __restrict__ off_k,
                                                 unsigned short* __restrict__ e16g,
                                                 unsigned short* __restrict__ e16k) {
  __shared__ int curs[SUBR];
  const int b = blockIdx.x;               // 128 blocks
  const int s = b & 7, r = (b >> 3) & 7, gr = b >> 6;
  const unsigned* bkt = (gr ? bkt_k : bkt_g) + (size_t)r * (gr ? CAPK : CAPG);
  const int* off = gr ? off_k : off_g;
  unsigned short* e16 = gr ? e16k : e16g;
  const int n = gcnt[gr * 8 + r];
  const int lo = r * RNG;
  const int slo = s * SUBR;
  int send = slo + SUBR;
  if (send > RNG) send = RNG;
  const int swid = send - slo;
  if (swid <= 0) return;
  for (int i = threadIdx.x; i < swid; i += 1024) curs[i] = off[lo + slo + i];
  __syncthreads();
  for (int i = threadIdx.x; i < n; i += 1024) {
    unsigned v = bkt[i];
    int d = (int)(v >> 16) - lo - slo;
    if ((unsigned)d < (unsigned)swid) {
      int pz = atomicAdd(&curs[d], 1);
      e16[pz] = (unsigned short)(v & 0xffffu);
    }
  }
}

// ---------------- CSR mean-aggregation (bf16, ushort esrc), unroll-8 ----------
template <int DLOG2>
__device__ __forceinline__ void agg_node(const unsigned short* __restrict__ h,
                                         const int* __restrict__ off,
                                         const unsigned short* __restrict__ esrc,
                                         const float* __restrict__ inv,
                                         unsigned short* __restrict__ out,
                                         int node, int lane) {
  int s = off[node], e = off[node + 1];
  float acc[8] = {0.f, 0.f, 0.f, 0.f, 0.f, 0.f, 0.f, 0.f};
  int j = s;
  for (; j + 7 < e; j += 8) {
    ushort8 v[8];
#pragma unroll
    for (int q = 0; q < 8; ++q) {
      int sq = esrc[j + q];
      v[q] = *reinterpret_cast<const ushort8*>(&h[((size_t)sq << DLOG2) + lane * 8]);
    }
#pragma unroll
    for (int q = 0; q < 8; ++q)
#pragma unroll
      for (int i = 0; i < 8; ++i) acc[i] += bf2f(v[q][i]);
  }
  for (; j + 3 < e; j += 4) {
    ushort8 v[4];
#pragma unroll
    for (int q = 0; q < 4; ++q) {
      int sq = esrc[j + q];
      v[q] = *reinterpret_cast<const ushort8*>(&h[((size_t)sq << DLOG2) + lane * 8]);
    }
#pragma unroll
    for (int q = 0; q < 4; ++q)
#pragma unroll
      for (int i = 0; i < 8; ++i) acc[i] += bf2f(v[q][i]);
  }
  for (; j < e; ++j) {
    int s0 = esrc[j];
    ushort8 v0 = *reinterpret_cast<const ushort8*>(&h[((size_t)s0 << DLOG2) + lane * 8]);
#pragma unroll
    for (int i = 0; i < 8; ++i) acc[i] += bf2f(v0[i]);
  }
  float sc = inv[node];
  ushort8 o;
#pragma unroll
  for (int i = 0; i < 8; ++i) o[i] = f2bf(acc[i] * sc);
  *reinterpret_cast<ushort8*>(&out[((size_t)node << DLOG2) + lane * 8]) = o;
}

template <int DLOG2>
__global__ __launch_bounds__(256) void csr_aggregate(const unsigned short* __restrict__ h,
                                                     const int* __restrict__ off,
                                                     const unsigned short* __restrict__ esrc,
                                                     const float* __restrict__ inv,
                                                     unsigned short* __restrict__ out) {
  constexpr int TPN = (1 << DLOG2) / 8;
  constexpr int NPB = 256 / TPN;
  int node = blockIdx.x * NPB + ((int)threadIdx.x / TPN);
  int lane = threadIdx.x & (TPN - 1);
  if (node >= NN) return;
  agg_node<DLOG2>(h, off, esrc, inv, out, node, lane);
}

// dual-graph D=128 aggregate
__global__ __launch_bounds__(256) void csr_aggregate2(
    const unsigned short* __restrict__ h0, const int* __restrict__ off0,
    const unsigned short* __restrict__ e0, const float* __restrict__ inv0,
    unsigned short* __restrict__ out0,
    const unsigned short* __restrict__ h1, const int* __restrict__ off1,
    const unsigned short* __restrict__ e1, const float* __restrict__ inv1,
    unsigned short* __restrict__ out1) {
  constexpr int TPN = 16, NPB = 16;
  int node = blockIdx.x * NPB + ((int)threadIdx.x / TPN);
  int lane = threadIdx.x & (TPN - 1);
  if (node >= NN) return;
  if (blockIdx.y == 0)
    agg_node<7>(h0, off0, e0, inv0, out0, node, lane);
  else
    agg_node<7>(h1, off1, e1, inv1, out1, node, lane);
}

// ---------------- MFMA GEMM body, BM=128 x BN=128, BK=64 ----------------
template <int K1, int K2, bool RELU, bool OUT_BF16>
__device__ __forceinline__ void gemm_body(
    int bx, int by, const unsigned short* __restrict__ A1,
    const unsigned short* __restrict__ A2, const unsigned short* __restrict__ Bt,
    const float* __restrict__ bias, void* __restrict__ outv, int ldo, int nrows,
    char* smem) {
  constexpr int KTOT = K1 + K2;
  constexpr int KT = KTOT / 64;
  unsigned short* sA = (unsigned short*)smem;
  unsigned short* sB = sA + 8192;

  const int t = threadIdx.x;
  const int lane = t & 63;
  const int w = t >> 6;
  const int wm = (w & 1) * 64, wn = (w >> 1) * 64;
  const int row0 = by * 128;
  const int n0 = bx * 128;

  const int srow = (w << 5) + (lane >> 3);
  const int schunk = (lane & 7) << 3;

  f32x4 acc[4][4] = {};

  for (int kt = 0; kt < KT; ++kt) {
    const int kbase = kt * 64;
    const unsigned short* Asrc = (kbase < K1) ? A1 : A2;
    const int kA = (kbase < K1) ? kbase : (kbase - K1);
    const int lda = (kbase < K1) ? K1 : K2;
#pragma unroll
    for (int q = 0; q < 4; ++q) {
      int rA = srow + q * 8;
      int rowg = row0 + rA;
      if (rowg >= nrows) rowg = nrows - 1;
      gload_lds16(Asrc + (size_t)rowg * lda + kA + schunk,
                  sA + ((w << 5) + q * 8) * 64);
      gload_lds16(Bt + (size_t)(n0 + rA) * KTOT + kbase + schunk,
                  sB + ((w << 5) + q * 8) * 64);
    }
    __syncthreads();
#pragma unroll
    for (int kk = 0; kk < 2; ++kk) {
      const int ko = kk * 32 + (lane >> 4) * 8;
      short8 a[4], b[4];
#pragma unroll
      for (int mi = 0; mi < 4; ++mi)
        a[mi] = *reinterpret_cast<const short8*>(&sA[(wm + mi * 16 + (lane & 15)) * 64 + ko]);
#pragma unroll
      for (int ni = 0; ni < 4; ++ni)
        b[ni] = *reinterpret_cast<const short8*>(&sB[(wn + ni * 16 + (lane & 15)) * 64 + ko]);
#pragma unroll
      for (int mi = 0; mi < 4; ++mi)
#pragma unroll
        for (int ni = 0; ni < 4; ++ni)
          acc[mi][ni] = __builtin_amdgcn_mfma_f32_16x16x32_bf16(a[mi], b[ni], acc[mi][ni], 0, 0, 0);
    }
    __syncthreads();
  }

  float* Co = (float*)smem;
#pragma unroll
  for (int h = 0; h < 2; ++h) {
    __syncthreads();
    if ((w >> 1) == h) {
#pragma unroll
      for (int mi = 0; mi < 4; ++mi)
#pragma unroll
        for (int ni = 0; ni < 4; ++ni) {
          int col = ni * 16 + (lane & 15);
          int rowb = wm + mi * 16 + (lane >> 4) * 4;
#pragma unroll
          for (int j = 0; j < 4; ++j) Co[(rowb + j) * 64 + col] = acc[mi][ni][j];
        }
    }
    __syncthreads();
    int sr = t >> 1, cb = (t & 1) * 32;
    int r = row0 + sr;
    if (r < nrows) {
      float v[32];
#pragma unroll
      for (int i = 0; i < 32; ++i) {
        v[i] = Co[sr * 64 + cb + i] + bias[n0 + h * 64 + cb + i];
        if (RELU) v[i] = fmaxf(v[i], 0.f);
      }
      if (OUT_BF16) {
        unsigned short* dst = (unsigned short*)outv + (size_t)r * ldo + n0 + h * 64 + cb;
#pragma unroll
        for (int q = 0; q < 4; ++q) {
          ushort8 o;
#pragma unroll
          for (int i = 0; i < 8; ++i) o[i] = f2bf(v[q * 8 + i]);
          *reinterpret_cast<ushort8*>(dst + q * 8) = o;
        }
      } else {
        float* dst = (float*)outv + (size_t)r * ldo + n0 + h * 64 + cb;
#pragma unroll
        for (int q = 0; q < 8; ++q) {
          float4 o = make_float4(v[4 * q], v[4 * q + 1], v[4 * q + 2], v[4 * q + 3]);
          *reinterpret_cast<float4*>(dst + 4 * q) = o;
        }
      }
    }
  }
}

template <int K1, int K2, bool RELU, bool OUT_BF16>
__global__ __launch_bounds__(256) void gemm_gl(
    const unsigned short* __restrict__ A1, const unsigned short* __restrict__ A2,
    const unsigned short* __restrict__ Bt, const float* __restrict__ bias,
    void* __restrict__ outv, int ldo, int nrows) {
  __shared__ char smem[32768];
  gemm_body<K1, K2, RELU, OUT_BF16>(blockIdx.x, blockIdx.y, A1, A2, Bt, bias, outv,
                                    ldo, nrows, smem);
}

// z-merged pair of same-shape GEMMs (identical instantiation -> identical numerics)
template <int K1, int K2, bool RELU, bool OUT_BF16>
__global__ __launch_bounds__(256) void gemm_gl2(
    const unsigned short* __restrict__ A1a, const unsigned short* __restrict__ A2a,
    const unsigned short* __restrict__ Bta, const float* __restrict__ biasa,
    void* __restrict__ outa,
    const unsigned short* __restrict__ A1b, const unsigned short* __restrict__ A2b,
    const unsigned short* __restrict__ Btb, const float* __restrict__ biasb,
    void* __restrict__ outb, int ldo, int nrows) {
  __shared__ char smem[32768];
  if (blockIdx.z == 0)
    gemm_body<K1, K2, RELU, OUT_BF16>(blockIdx.x, blockIdx.y, A1a, A2a, Bta, biasa,
                                      outa, ldo, nrows, smem);
  else
    gemm_body<K1, K2, RELU, OUT_BF16>(blockIdx.x, blockIdx.y, A1b, A2b, Btb, biasb,
                                      outb, ldo, nrows, smem);
}

// ---------------- tail GEMM K=512 + agg adds + fused BN partial stats ----------------
__global__ __launch_bounds__(256) void gemm_tail512(
    const unsigned short* __restrict__ A0, const unsigned short* __restrict__ A1,
    const unsigned short* __restrict__ Bt, const float* __restrict__ bias,
    const unsigned short* __restrict__ aYL, const unsigned short* __restrict__ aYG,
    float* __restrict__ outv, float* __restrict__ bnsums, int nrows) {
  constexpr int KTOT = 512;
  constexpr int KT = 8;
  __shared__ char smem[32768];
  __shared__ float psum[4][64], psum2[4][64];
  unsigned short* sA = (unsigned short*)smem;
  unsigned short* sB = sA + 8192;

  const int t = threadIdx.x;
  const int lane = t & 63;
  const int w = t >> 6;
  const int wm = (w & 1) * 64, wn = (w >> 1) * 64;
  const int row0 = blockIdx.y * 128;

  const int srow = (w << 5) + (lane >> 3);
  const int schunk = (lane & 7) << 3;

  f32x4 acc[4][4] = {};

  for (int kt = 0; kt < KT; ++kt) {
    const unsigned short* Asrc = (kt < 4) ? A0 : A1;
    const int kA = (kt & 3) * 64;
#pragma unroll
    for (int q = 0; q < 4; ++q) {
      int rA = srow + q * 8;
      int rowg = row0 + rA;
      if (rowg >= nrows) rowg = nrows - 1;
      gload_lds16(Asrc + (size_t)rowg * 256 + kA + schunk,
                  sA + ((w << 5) + q * 8) * 64);
      gload_lds16(Bt + (size_t)rA * KTOT + kt * 64 + schunk,
                  sB + ((w << 5) + q * 8) * 64);
    }
    __syncthreads();
#pragma unroll
    for (int kk = 0; kk < 2; ++kk) {
      const int ko = kk * 32 + (lane >> 4) * 8;
      short8 a[4], b[4];
#pragma unroll
      for (int mi = 0; mi < 4; ++mi)
        a[mi] = *reinterpret_cast<const short8*>(&sA[(wm + mi * 16 + (lane & 15)) * 64 + ko]);
#pragma unroll
      for (int ni = 0; ni < 4; ++ni)
        b[ni] = *reinterpret_cast<const short8*>(&sB[(wn + ni * 16 + (lane & 15)) * 64 + ko]);
#pragma unroll
      for (int mi = 0; mi < 4; ++mi)
#pragma unroll
        for (int ni = 0; ni < 4; ++ni)
          acc[mi][ni] = __builtin_amdgcn_mfma_f32_16x16x32_bf16(a[mi], b[ni], acc[mi][ni], 0, 0, 0);
    }
    __syncthreads();
  }

  float* Co = (float*)smem;
#pragma unroll
  for (int h = 0; h < 2; ++h) {
    __syncthreads();
    if ((w >> 1) == h) {
#pragma unroll
      for (int mi = 0; mi < 4; ++mi)
#pragma unroll
        for (int ni = 0; ni < 4; ++ni) {
          int col = ni * 16 + (lane & 15);
          int rowb = wm + mi * 16 + (lane >> 4) * 4;
#pragma unroll
          for (int j = 0; j < 4; ++j) Co[(rowb + j) * 64 + col] = acc[mi][ni][j];
        }
    }
    __syncthreads();
    int sr = t >> 1, cb = (t & 1) * 32;
    int r = row0 + sr;
    if (r < nrows) {
      float* dst = outv + (size_t)r * MLPH + h * 64 + cb;
#pragma unroll
      for (int q = 0; q < 4; ++q) {
        ushort8 ya = *reinterpret_cast<const ushort8*>(&aYL[(size_t)r * MLPH + h * 64 + cb + q * 8]);
        ushort8 yb = *reinterpret_cast<const ushort8*>(&aYG[(size_t)r * MLPH + h * 64 + cb + q * 8]);
        float v[8];
#pragma unroll
        for (int i = 0; i < 8; ++i) {
          v[i] = Co[sr * 64 + cb + q * 8 + i] + bf2f(ya[i]) + bf2f(yb[i]) +
                 bias[h * 64 + cb + q * 8 + i];
          Co[sr * 64 + cb + q * 8 + i] = v[i];
        }
        *reinterpret_cast<float4*>(dst + q * 8) = make_float4(v[0], v[1], v[2], v[3]);
        *reinterpret_cast<float4*>(dst + q * 8 + 4) = make_float4(v[4], v[5], v[6], v[7]);
      }
    }
    __syncthreads();
    {
      int c = t & 63, rq = t >> 6;
      float s = 0.f, s2 = 0.f;
      int rbeg = rq * 32;
      for (int rr = rbeg; rr < rbeg + 32; ++rr) {
        if (row0 + rr < nrows) {
          float v = Co[rr * 64 + c];
          s += v;
          s2 += v * v;
        }
      }
      psum[rq][c] = s;
      psum2[rq][c] = s2;
    }
    __syncthreads();
    if (t < 64) {
      float s = psum[0][t] + psum[1][t] + psum[2][t] + psum[3][t];
      float s2 = psum2[0][t] + psum2[1][t] + psum2[2][t] + psum2[3][t];
      atomicAdd(&bnsums[h * 64 + t], s);
      atomicAdd(&bnsums[128 + h * 64 + t], s2);
    }
    __syncthreads();
  }
}

// ---------------- BN finalize ----------------
__global__ __launch_bounds__(128) void bn_finalize_kernel(float* __restrict__ stats,
                                                          const float* __restrict__ gamma,
                                                          const float* __restrict__ beta) {
  int c = threadIdx.x;
  float mu = stats[c] * (1.0f / NN);
  float var = stats[128 + c] * (1.0f / NN) - mu * mu;
  var = fmaxf(var, 0.f);
  float sc = gamma[c] * rsqrtf(var + BN_EPS);
  stats[256 + c] = sc;
  stats[384 + c] = beta[c] - mu * sc;
}

// ---------------- final head GEMM with fused BN+ReLU on A-load (64x64) ----------------
template <int K1, bool RELU>
__global__ __launch_bounds__(256) void gemm_mfma_bn(
    const float* __restrict__ A1v, const unsigned short* __restrict__ Bt,
    const float* __restrict__ bias, const float* __restrict__ bnscale,
    const float* __restrict__ bnshift, float* __restrict__ outv, int ldo, int nrows) {
  constexpr int KT = K1 / 64;
  constexpr int LDT = 72;
  __shared__ char smem[2 * 64 * LDT * 2];
  unsigned short* As = (unsigned short*)smem;
  unsigned short* Bs = As + 64 * LDT;
  float* Co = (float*)smem;
  constexpr int LDC = 68;

  const int t = threadIdx.x;
  const int lane = t & 63;
  const int w = t >> 6;
  const int wm = (w & 1) * 32, wn = (w >> 1) * 32;
  const int row0 = blockIdx.y * 64;
  const int n0 = blockIdx.x * 64;

  const int sr = t >> 2;
  const int skc = (t & 3) * 16;
  int rg = row0 + sr;
  if (rg >= nrows) rg = nrows - 1;

  f32x4 acc[2][2] = {};

  for (int kt = 0; kt < KT; ++kt) {
    const int kbase = kt * 64;
    {
      const float* xb = A1v + (size_t)rg * K1 + kbase + skc;
      ushort8 o0, o1;
#pragma unroll
      for (int i = 0; i < 8; ++i) {
        float v = xb[i] * bnscale[kbase + skc + i] + bnshift[kbase + skc + i];
        o0[i] = f2bf(fmaxf(v, 0.f));
      }
#pragma unroll
      for (int i = 0; i < 8; ++i) {
        float v = xb[8 + i] * bnscale[kbase + skc + 8 + i] + bnshift[kbase + skc + 8 + i];
        o1[i] = f2bf(fmaxf(v, 0.f));
      }
      *reinterpret_cast<ushort8*>(&As[sr * LDT + skc]) = o0;
      *reinterpret_cast<ushort8*>(&As[sr * LDT + skc + 8]) = o1;
    }
    {
      const unsigned short* bb = Bt + (size_t)(n0 + sr) * K1 + kbase + skc;
      int4 p0 = *reinterpret_cast<const int4*>(bb);
      int4 p1 = *reinterpret_cast<const int4*>(bb + 8);
      *reinterpret_cast<int4*>(&Bs[sr * LDT + skc]) = p0;
      *reinterpret_cast<int4*>(&Bs[sr * LDT + skc + 8]) = p1;
    }
    __syncthreads();
#pragma unroll
    for (int kk = 0; kk < 2; ++kk) {
      const int ko = kk * 32 + (lane >> 4) * 8;
      short8 a0 = *reinterpret_cast<const short8*>(&As[(wm + (lane & 15)) * LDT + ko]);
      short8 a1 = *reinterpret_cast<const short8*>(&As[(wm + 16 + (lane & 15)) * LDT + ko]);
      short8 b0 = *reinterpret_cast<const short8*>(&Bs[(wn + (lane & 15)) * LDT + ko]);
      short8 b1 = *reinterpret_cast<const short8*>(&Bs[(wn + 16 + (lane & 15)) * LDT + ko]);
      acc[0][0] = __builtin_amdgcn_mfma_f32_16x16x32_bf16(a0, b0, acc[0][0], 0, 0, 0);
      acc[0][1] = __builtin_amdgcn_mfma_f32_16x16x32_bf16(a0, b1, acc[0][1], 0, 0, 0);
      acc[1][0] = __builtin_amdgcn_mfma_f32_16x16x32_bf16(a1, b0, acc[1][0], 0, 0, 0);
      acc[1][1] = __builtin_amdgcn_mfma_f32_16x16x32_bf16(a1, b1, acc[1][1], 0, 0, 0);
    }
    __syncthreads();
  }

#pragma unroll
  for (int mi = 0; mi < 2; ++mi)
#pragma unroll
    for (int ni = 0; ni < 2; ++ni) {
      int col = wn + ni * 16 + (lane & 15);
      int rowb = wm + mi * 16 + (lane >> 4) * 4;
#pragma unroll
      for (int j = 0; j < 4; ++j) Co[(rowb + j) * LDC + col] = acc[mi][ni][j];
    }
  __syncthreads();
  {
    int r = row0 + sr;
    if (r < nrows) {
      float v[16];
#pragma unroll
      for (int i = 0; i < 16; ++i) {
        v[i] = Co[sr * LDC + skc + i] + bias[n0 + skc + i];
        if (RELU) v[i] = fmaxf(v[i], 0.f);
      }
      float* dst = outv + (size_t)r * ldo + n0 + skc;
#pragma unroll
      for (int i = 0; i < 4; ++i) {
        float4 o = make_float4(v[4 * i], v[4 * i + 1], v[4 * i + 2], v[4 * i + 3]);
        *reinterpret_cast<float4*>(dst + 4 * i) = o;
      }
    }
  }
}

// ---------------- launch ----------------
extern "C" void kernel_launch(void* const* d_in, const int* in_sizes, int n_in,
                              void* d_out, int out_size, void* d_ws, size_t ws_size,
                              hipStream_t stream) {
  const float* feat = (const float*)d_in[0];
  const int* g_src = (const int*)d_in[1];
  const int* g_dst = (const int*)d_in[2];
  const int* k_src = (const int*)d_in[3];
  const int* k_dst = (const int*)d_in[4];
  const float* lb_0 = (const float*)d_in[7];
  const float* lb_1 = (const float*)d_in[10];
  const float* lb_2 = (const float*)d_in[13];
  const float* gb_0 = (const float*)d_in[16];
  const float* gb_1 = (const float*)d_in[19];
  const float* mlp_b1 = (const float*)d_in[21];
  const float* bn_gamma = (const float*)d_in[22];
  const float* bn_beta = (const float*)d_in[23];
  const float* mlp_b2 = (const float*)d_in[25];
  float* out = (float*)d_out;

  // workspace layout
  float* xf32 = (float*)d_ws;                         // N*128 f32
  int* cnt_g = (int*)(xf32 + (size_t)NN * 128);       // N
  int* cnt_k = cnt_g + NN;                            // N
  float* stats = (float*)(cnt_k + NN);                // 512
  int* gcnt = (int*)(stats + 512);                    // 16
  float* zbias = (float*)(gcnt + 16);                 // 128 (zeroed with block above)
  float* invg = zbias + 128;                          // N
  float* invk = invg + NN;                            // N
  int* off_g = (int*)(invk + NN);                     // N+4
  int* off_k = off_g + NN + 4;                        // N+4
  int* part = off_k + NN + 4;                         // 512
  unsigned* bkt_g = (unsigned*)(part + 512);          // 8*CAPG
  unsigned* bkt_k = bkt_g + 8 * CAPG;                 // 8*CAPK
  unsigned short* e16g = (unsigned short*)(bkt_k + 8 * CAPK);  // EG
  unsigned short* e16k = e16g + EG;                   // EK
  unsigned short* featbf = e16k + EK;                 // N*128
  unsigned short* wts = featbf + (size_t)NN * IN_F;   // 598016
  unsigned short* wf = wts + 598016;                  // 131072
  float* bfused = (float*)(wf + 131072);              // 128
  unsigned short* hL0 = (unsigned short*)(bfused + 128);  // N*256
  unsigned short* hG0 = hL0 + (size_t)NN * HF;        // N*256
  unsigned short* hL1 = hG0 + (size_t)NN * HF;        // N*256
  unsigned short* aggT = hL1 + (size_t)NN * HF;       // N*256
  unsigned short* aggFG = aggT + (size_t)NN * HF;     // N*128
  unsigned short* aggFK = aggFG + (size_t)NN * MLPH;  // N*128
  unsigned short* bfYL = aggFK + (size_t)NN * MLPH;   // N*128
  unsigned short* bfYG = bfYL + (size_t)NN * MLPH;    // N*128
  unsigned short* bfAYL = bfYG + (size_t)NN * MLPH;   // N*128
  unsigned short* bfAYG = bfAYL + (size_t)NN * MLPH;  // N*128

  const int wL0 = 0, wL1 = 65536, wG0 = 327680, wH2 = 589824;
  const int wfYL = 65536, wfYG = 98304;

  dim3 blk(256);
  const int NB = (NN + 255) / 256;        // 196
  const int MB = (NN + 127) / 128;        // 391
  const dim3 gridH(2, MB);                // 256-col out
  const dim3 gridM(1, MB);                // 128-col out
  const int agg128_blocks = (NN + 15) / 16;
  const int agg256_blocks = (NN + 7) / 8;
  const int BKB = (EK + 2047) / 2048;
  const int CC = 8;

  // zero cnt_g, cnt_k, stats, gcnt, zbias
  hipMemsetAsync(cnt_g, 0,
                 (size_t)(2 * NN) * sizeof(int) + 512 * sizeof(float) + 16 * sizeof(int) +
                     128 * sizeof(float),
                 stream);

  WPack p;
  p.d[0] = {(const float*)d_in[5], 128, 8, 0, 256, wL0};
  p.d[1] = {(const float*)d_in[6], 128, 8, 128, 256, wL0};
  p.d[2] = {(const float*)d_in[8], 256, 8, 0, 512, wL1};
  p.d[3] = {(const float*)d_in[9], 256, 8, 256, 512, wL1};
  p.d[4] = {(const float*)d_in[11], 256, 8, 0, 512, 196608};  // folded; layout keep
  p.d[5] = {(const float*)d_in[12], 256, 8, 256, 512, 196608};
  p.d[6] = {(const float*)d_in[14], 128, 8, 0, 256, wG0};
  p.d[7] = {(const float*)d_in[15], 128, 8, 128, 256, wG0};
  p.d[8] = {(const float*)d_in[17], 256, 8, 0, 512, 393216};  // folded
  p.d[9] = {(const float*)d_in[18], 256, 8, 256, 512, 393216};
  p.d[10] = {(const float*)d_in[20], 512, 7, 0, 512, 524288}; // folded
  p.d[11] = {(const float*)d_in[24], 128, 6, 0, 128, wH2};
  prep_kernel<<<3510, blk, 0, stream>>>(feat, featbf, p, wts);

  fuse_w_kernel<<<1025, 128, 0, stream>>>(
      (const float*)d_in[11], (const float*)d_in[12],
      (const float*)d_in[17], (const float*)d_in[18],
      (const float*)d_in[20], lb_2, gb_1, mlp_b1, wf, bfused);

  // ---- CSR build ----
  bucket_kernel<<<dim3(BKB, 2), blk, 0, stream>>>(g_src, g_dst, k_src, k_dst, gcnt, bkt_g, bkt_k);
  count_bucket<<<dim3(8, 2, CC), blk, 0, stream>>>(bkt_g, bkt_k, gcnt, cnt_g, cnt_k, CC);
  scan_partial2<<<dim3(NB, 2), blk, 0, stream>>>(cnt_g, cnt_k, part, NN);
  scan_block2<<<2, blk, 0, stream>>>(part, NB);
  scan_final2<<<dim3(NB, 2), blk, 0, stream>>>(cnt_g, cnt_k, part, off_g, off_k, invg, invk, NN);
  fill_sub<<<128, 1024, 0, stream>>>(bkt_g, bkt_k, gcnt, off_g, off_k, e16g, e16k);

  // ---- both feat aggregates (D=128, graphs g & k) in one dispatch ----
  csr_aggregate2<<<dim3(agg128_blocks, 2), blk, 0, stream>>>(
      featbf, off_g, e16g, invg, aggFG, featbf, off_k, e16k, invk, aggFK);
  // ---- l0 and g0 GEMMs, z-merged ----
  gemm_gl2<128, 128, true, true><<<dim3(2, MB, 2), blk, 0, stream>>>(
      featbf, aggFG, wts + wL0, lb_0, hL0,
      featbf, aggFK, wts + wG0, gb_0, hG0, HF, NN);
  // ---- l1 agg (D=256) + l1 GEMM ----
  csr_aggregate<8><<<agg256_blocks, blk, 0, stream>>>(hL0, off_g, e16g, invg, aggT);
  gemm_gl<256, 256, true, true><<<gridH, blk, 0, stream>>>(
      hL0, aggT, wts + wL1, lb_1, hL1, HF, NN);
  // ---- yl = hL1 @ Wf1, yg = hG0 @ Wf3, z-merged ----
  gemm_gl2<256, 0, false, true><<<dim3(1, MB, 2), blk, 0, stream>>>(
      hL1, nullptr, wf + wfYL, zbias, bfYL,
      hG0, nullptr, wf + wfYG, zbias, bfYG, MLPH, NN);
  // ---- agg yl over g, yg over k (one dispatch) ----
  csr_aggregate2<<<dim3(agg128_blocks, 2), blk, 0, stream>>>(
      bfYL, off_g, e16g, invg, bfAYL, bfYG, off_k, e16k, invk, bfAYG);

  // ---- tail GEMM + fused BN stats ----
  gemm_tail512<<<gridM, blk, 0, stream>>>(hL1, hG0, wf, bfused, bfAYL, bfAYG, xf32, stats, NN);

  // ---- BN finalize + head GEMM2 ----
  bn_finalize_kernel<<<1, 128, 0, stream>>>(stats, bn_gamma, bn_beta);
  gemm_mfma_bn<128, false><<<dim3(1, (NN + 63) / 64), blk, 0, stream>>>(
      xf32, wts + wH2, mlp_b2, stats + 256, stats + 384, out, COUT, NN);
}

// Round 17
// 456.325 us; speedup vs baseline: 1.0370x; 1.0370x over previous
//
#include <hip/hip_runtime.h>

#define NN   50000
#define IN_F 128
#define HF   256
#define COUT 64
#define MLPH 128
#define EG   600000
#define EK   800000
#define RNG  6250    // NN / 8
#define SUBR 782     // ceil(RNG / 8)
#define CAPG 80000
#define CAPK 106000
#define BN_EPS 1e-5f

typedef __attribute__((ext_vector_type(8))) short short8;
typedef __attribute__((ext_vector_type(8))) unsigned short ushort8;
typedef __attribute__((ext_vector_type(4))) float f32x4;

__device__ __forceinline__ unsigned short f2bf(float f) {
  union { float f; unsigned int u; } v; v.f = f;
  unsigned int r = v.u + 0x7FFFu + ((v.u >> 16) & 1u);
  return (unsigned short)(r >> 16);
}
__device__ __forceinline__ float bf2f(unsigned short s) {
  union { unsigned int u; float f; } v; v.u = ((unsigned int)s) << 16;
  return v.f;
}

__device__ __forceinline__ void gload_lds16(const void* g, void* l) {
  __builtin_amdgcn_global_load_lds((const __attribute__((address_space(1))) void*)g,
                                   (__attribute__((address_space(3))) void*)l, 16, 0, 0);
}

struct WDesc { const float* src; int rows; int cshift; int kofs; int ldk; int dofs; };
struct WPack { WDesc d[12]; };

// ---------------- prep: feat->bf16, weight transpose ----------------
__global__ __launch_bounds__(256) void prep_kernel(const float* __restrict__ feat,
                                                   unsigned short* __restrict__ featbf,
                                                   WPack p, unsigned short* __restrict__ wts) {
  int b = blockIdx.x;
  if (b < 3126) {
    int i = b * 256 + threadIdx.x;
    if (i < NN * IN_F / 8) {
      float4 a = *reinterpret_cast<const float4*>(&feat[i * 8]);
      float4 c = *reinterpret_cast<const float4*>(&feat[i * 8 + 4]);
      ushort8 o;
      o[0] = f2bf(a.x); o[1] = f2bf(a.y); o[2] = f2bf(a.z); o[3] = f2bf(a.w);
      o[4] = f2bf(c.x); o[5] = f2bf(c.y); o[6] = f2bf(c.z); o[7] = f2bf(c.w);
      *reinterpret_cast<ushort8*>(&featbf[i * 8]) = o;
    }
  } else {
    int wb = b - 3126;
    WDesc w = p.d[wb >> 5];
    int xb = wb & 31;
    int total = w.rows << w.cshift;
    int cmask = (1 << w.cshift) - 1;
    for (int idx = xb * 256 + threadIdx.x; idx < total; idx += 32 * 256) {
      int r = idx >> w.cshift, c = idx & cmask;
      wts[w.dofs + (size_t)c * w.ldk + w.kofs + r] = f2bf(w.src[idx]);
    }
  }
}

// ---------------- fused head weights ----------------
__global__ __launch_bounds__(128) void fuse_w_kernel(
    const float* __restrict__ wl2s, const float* __restrict__ wl2n,
    const float* __restrict__ wg1s, const float* __restrict__ wg1n,
    const float* __restrict__ w1, const float* __restrict__ bl2,
    const float* __restrict__ bg1, const float* __restrict__ b1,
    unsigned short* __restrict__ wf, float* __restrict__ bfused) {
  int b = blockIdx.x;
  int c = threadIdx.x;
  __shared__ float row[256];
  if (b < 1024) {
    int seg = b >> 8, i = b & 255;
    const float* W = (seg == 0) ? wl2s : (seg == 1) ? wl2n : (seg == 2) ? wg1s : wg1n;
    const float* w1b = w1 + ((seg < 2) ? 0 : 256) * MLPH;
    row[c] = W[i * 256 + c];
    row[c + 128] = W[i * 256 + 128 + c];
    __syncthreads();
    float acc = 0.f;
    for (int o = 0; o < 256; ++o) acc += row[o] * w1b[o * MLPH + c];
    unsigned short v = f2bf(acc);
    if (seg == 0)      wf[(size_t)c * 512 + i] = v;
    else if (seg == 2) wf[(size_t)c * 512 + 256 + i] = v;
    else if (seg == 1) wf[65536 + (size_t)c * 256 + i] = v;
    else               wf[98304 + (size_t)c * 256 + i] = v;
  } else {
    float acc = b1[c];
    for (int o = 0; o < 256; ++o) acc += bl2[o] * w1[o * MLPH + c];
    for (int o = 0; o < 256; ++o) acc += bg1[o] * w1[(256 + o) * MLPH + c];
    bfused[c] = acc;
  }
}

// ---------------- edge bucketing ----------------
__global__ __launch_bounds__(256) void bucket_kernel(const int* __restrict__ g_src,
                                                     const int* __restrict__ g_dst,
                                                     const int* __restrict__ k_src,
                                                     const int* __restrict__ k_dst,
                                                     int* __restrict__ gcnt,
                                                     unsigned* __restrict__ bkt_g,
                                                     unsigned* __restrict__ bkt_k) {
  __shared__ unsigned buf[2048];
  __shared__ int rcnt[8], rbase[8], roff[8];
  const int gr = blockIdx.y;
  const int* src = gr ? k_src : g_src;
  const int* dst = gr ? k_dst : g_dst;
  unsigned* bkt = gr ? bkt_k : bkt_g;
  const int CAP = gr ? CAPK : CAPG;
  const int E = gr ? EK : EG;
  int* gc = gcnt + gr * 8;
  const int tid = threadIdx.x;
  const int e0 = blockIdx.x * 2048;
  if (e0 >= E) return;
  if (tid < 8) rcnt[tid] = 0;
  __syncthreads();
  unsigned vloc[8];
  int rloc[8], ploc[8];
#pragma unroll
  for (int i = 0; i < 8; ++i) {
    int e = e0 + i * 256 + tid;
    rloc[i] = -1;
    if (e < E) {
      int d = dst[e], s = src[e];
      int r = d / RNG;
      vloc[i] = ((unsigned)d << 16) | (unsigned)s;
      rloc[i] = r;
      ploc[i] = atomicAdd(&rcnt[r], 1);
    }
  }
  __syncthreads();
  if (tid == 0) {
    int acc = 0;
#pragma unroll
    for (int r = 0; r < 8; ++r) { roff[r] = acc; acc += rcnt[r]; }
  }
  __syncthreads();
#pragma unroll
  for (int i = 0; i < 8; ++i)
    if (rloc[i] >= 0) buf[roff[rloc[i]] + ploc[i]] = vloc[i];
  __syncthreads();
  if (tid < 8) rbase[tid] = atomicAdd(&gc[tid], rcnt[tid]);
  __syncthreads();
#pragma unroll
  for (int r = 0; r < 8; ++r) {
    int len = rcnt[r];
    unsigned* dstp = bkt + (size_t)r * CAP + rbase[r];
    for (int i = tid; i < len; i += 256) dstp[i] = buf[roff[r] + i];
  }
}

// ---------------- per-range count (LDS histogram) ----------------
__global__ __launch_bounds__(256) void count_bucket(const unsigned* __restrict__ bkt_g,
                                                    const unsigned* __restrict__ bkt_k,
                                                    const int* __restrict__ gcnt,
                                                    int* __restrict__ cnt_g,
                                                    int* __restrict__ cnt_k, int CC) {
  __shared__ int hist[RNG];
  const int r = blockIdx.x, gr = blockIdx.y, z = blockIdx.z;
  const unsigned* b = (gr ? bkt_k : bkt_g) + (size_t)r * (gr ? CAPK : CAPG);
  int* cnt = gr ? cnt_k : cnt_g;
  const int n = gcnt[gr * 8 + r];
  const unsigned lo = r * RNG;
  for (int i = threadIdx.x; i < RNG; i += 256) hist[i] = 0;
  __syncthreads();
  for (int i = z * 256 + threadIdx.x; i < n; i += CC * 256) {
    unsigned d = (b[i] >> 16) - lo;
    atomicAdd(&hist[d], 1);
  }
  __syncthreads();
  for (int i = threadIdx.x; i < RNG; i += 256) {
    int v = hist[i];
    if (v) atomicAdd(&cnt[lo + i], v);
  }
}

// ---------------- parallel scans ----------------
__global__ __launch_bounds__(256) void scan_partial2(const int* __restrict__ cnt_g,
                                                     const int* __restrict__ cnt_k,
                                                     int* __restrict__ part, int n) {
  const int* cnt = blockIdx.y ? cnt_k : cnt_g;
  int* pp = part + blockIdx.y * 256;
  int i = blockIdx.x * 256 + threadIdx.x;
  int v = (i < n) ? cnt[i] : 0;
  __shared__ int ws[4];
  int lane = threadIdx.x & 63, wid = threadIdx.x >> 6;
  int x = v;
#pragma unroll
  for (int d = 1; d < 64; d <<= 1) { int y = __shfl_up(x, d, 64); if (lane >= d) x += y; }
  if (lane == 63) ws[wid] = x;
  __syncthreads();
  if (threadIdx.x == 0) pp[blockIdx.x] = ws[0] + ws[1] + ws[2] + ws[3];
}

__global__ __launch_bounds__(256) void scan_block2(int* __restrict__ part, int np) {
  int* pp = part + blockIdx.x * 256;
  __shared__ int ws[4];
  int tid = threadIdx.x, lane = tid & 63, wid = tid >> 6;
  int v = (tid < np) ? pp[tid] : 0;
  int x = v;
#pragma unroll
  for (int d = 1; d < 64; d <<= 1) { int y = __shfl_up(x, d, 64); if (lane >= d) x += y; }
  if (lane == 63) ws[wid] = x;
  __syncthreads();
  int add = 0;
#pragma unroll
  for (int k = 0; k < 4; ++k) if (k < wid) add += ws[k];
  if (tid < np) pp[tid] = x - v + add;
}

__global__ __launch_bounds__(256) void scan_final2(const int* __restrict__ cnt_g,
                                                   const int* __restrict__ cnt_k,
                                                   const int* __restrict__ part,
                                                   int* __restrict__ off_g,
                                                   int* __restrict__ off_k,
                                                   float* __restrict__ invg,
                                                   float* __restrict__ invk, int n) {
  const int* cnt = blockIdx.y ? cnt_k : cnt_g;
  const int* pp = part + blockIdx.y * 256;
  int* off = blockIdx.y ? off_k : off_g;
  float* inv = blockIdx.y ? invk : invg;
  int total = blockIdx.y ? EK : EG;
  int i = blockIdx.x * 256 + threadIdx.x;
  int v = (i < n) ? cnt[i] : 0;
  __shared__ int ws[4];
  int lane = threadIdx.x & 63, wid = threadIdx.x >> 6;
  int x = v;
#pragma unroll
  for (int d = 1; d < 64; d <<= 1) { int y = __shfl_up(x, d, 64); if (lane >= d) x += y; }
  if (lane == 63) ws[wid] = x;
  __syncthreads();
  int add = pp[blockIdx.x];
#pragma unroll
  for (int k = 0; k < 4; ++k) if (k < wid) add += ws[k];
  if (i < n) {
    off[i] = x - v + add;
    inv[i] = 1.0f / fmaxf((float)v, 1.0f);
  }
  if (i == 0) off[n] = total;
}

// ---------------- CSR fill: 8 sub-ranges, LDS cursors ----------------
__global__ __launch_bounds__(1024) void fill_sub(const unsigned* __restrict__ bkt_g,
                                                 const unsigned* __restrict__ bkt_k,
                                                 const int* __restrict__ gcnt,
                                                 const int* __restrict__ off_g,
                                                 const int* __restrict__ off_k,
                                                 unsigned short* __restrict__ e16g,
                                                 unsigned short* __restrict__ e16k) {
  __shared__ int curs[SUBR];
  const int b = blockIdx.x;               // 128 blocks
  const int s = b & 7, r = (b >> 3) & 7, gr = b >> 6;
  const unsigned* bkt = (gr ? bkt_k : bkt_g) + (size_t)r * (gr ? CAPK : CAPG);
  const int* off = gr ? off_k : off_g;
  unsigned short* e16 = gr ? e16k : e16g;
  const int n = gcnt[gr * 8 + r];
  const int lo = r * RNG;
  const int slo = s * SUBR;
  int send = slo + SUBR;
  if (send > RNG) send = RNG;
  const int swid = send - slo;
  if (swid <= 0) return;
  for (int i = threadIdx.x; i < swid; i += 1024) curs[i] = off[lo + slo + i];
  __syncthreads();
  for (int i = threadIdx.x; i < n; i += 1024) {
    unsigned v = bkt[i];
    int d = (int)(v >> 16) - lo - slo;
    if ((unsigned)d < (unsigned)swid) {
      int pz = atomicAdd(&curs[d], 1);
      e16[pz] = (unsigned short)(v & 0xffffu);
    }
  }
}

// ---------------- CSR mean-aggregation (bf16, ushort esrc), unroll-8 ----------
template <int DLOG2>
__device__ __forceinline__ void agg_node(const unsigned short* __restrict__ h,
                                         const int* __restrict__ off,
                                         const unsigned short* __restrict__ esrc,
                                         const float* __restrict__ inv,
                                         unsigned short* __restrict__ out,
                                         int node, int lane) {
  int s = off[node], e = off[node + 1];
  float acc[8] = {0.f, 0.f, 0.f, 0.f, 0.f, 0.f, 0.f, 0.f};
  int j = s;
  for (; j + 7 < e; j += 8) {
    ushort8 v[8];
#pragma unroll
    for (int q = 0; q < 8; ++q) {
      int sq = esrc[j + q];
      v[q] = *reinterpret_cast<const ushort8*>(&h[((size_t)sq << DLOG2) + lane * 8]);
    }
#pragma unroll
    for (int q = 0; q < 8; ++q)
#pragma unroll
      for (int i = 0; i < 8; ++i) acc[i] += bf2f(v[q][i]);
  }
  for (; j + 3 < e; j += 4) {
    ushort8 v[4];
#pragma unroll
    for (int q = 0; q < 4; ++q) {
      int sq = esrc[j + q];
      v[q] = *reinterpret_cast<const ushort8*>(&h[((size_t)sq << DLOG2) + lane * 8]);
    }
#pragma unroll
    for (int q = 0; q < 4; ++q)
#pragma unroll
      for (int i = 0; i < 8; ++i) acc[i] += bf2f(v[q][i]);
  }
  for (; j < e; ++j) {
    int s0 = esrc[j];
    ushort8 v0 = *reinterpret_cast<const ushort8*>(&h[((size_t)s0 << DLOG2) + lane * 8]);
#pragma unroll
    for (int i = 0; i < 8; ++i) acc[i] += bf2f(v0[i]);
  }
  float sc = inv[node];
  ushort8 o;
#pragma unroll
  for (int i = 0; i < 8; ++i) o[i] = f2bf(acc[i] * sc);
  *reinterpret_cast<ushort8*>(&out[((size_t)node << DLOG2) + lane * 8]) = o;
}

template <int DLOG2>
__global__ __launch_bounds__(256) void csr_aggregate(const unsigned short* __restrict__ h,
                                                     const int* __restrict__ off,
                                                     const unsigned short* __restrict__ esrc,
                                                     const float* __restrict__ inv,
                                                     unsigned short* __restrict__ out) {
  constexpr int TPN = (1 << DLOG2) / 8;
  constexpr int NPB = 256 / TPN;
  int node = blockIdx.x * NPB + ((int)threadIdx.x / TPN);
  int lane = threadIdx.x & (TPN - 1);
  if (node >= NN) return;
  agg_node<DLOG2>(h, off, esrc, inv, out, node, lane);
}

// dual-graph D=128 aggregate
__global__ __launch_bounds__(256) void csr_aggregate2(
    const unsigned short* __restrict__ h0, const int* __restrict__ off0,
    const unsigned short* __restrict__ e0, const float* __restrict__ inv0,
    unsigned short* __restrict__ out0,
    const unsigned short* __restrict__ h1, const int* __restrict__ off1,
    const unsigned short* __restrict__ e1, const float* __restrict__ inv1,
    unsigned short* __restrict__ out1) {
  constexpr int TPN = 16, NPB = 16;
  int node = blockIdx.x * NPB + ((int)threadIdx.x / TPN);
  int lane = threadIdx.x & (TPN - 1);
  if (node >= NN) return;
  if (blockIdx.y == 0)
    agg_node<7>(h0, off0, e0, inv0, out0, node, lane);
  else
    agg_node<7>(h1, off1, e1, inv1, out1, node, lane);
}

// ---------------- MFMA GEMM body, BM=128 x BN=128, BK=64, bank-swizzled LDS --------
// LDS dest of global_load_lds is linear (HW requirement); the per-lane GLOBAL source
// chunk is XOR-permuted (chunk ^= row&7) and fragment reads apply the same XOR.
template <int K1, int K2, bool RELU, bool OUT_BF16>
__device__ __forceinline__ void gemm_body(
    int bx, int by, const unsigned short* __restrict__ A1,
    const unsigned short* __restrict__ A2, const unsigned short* __restrict__ Bt,
    const float* __restrict__ bias, void* __restrict__ outv, int ldo, int nrows,
    char* smem) {
  constexpr int KTOT = K1 + K2;
  constexpr int KT = KTOT / 64;
  unsigned short* sA = (unsigned short*)smem;
  unsigned short* sB = sA + 8192;

  const int t = threadIdx.x;
  const int lane = t & 63;
  const int w = t >> 6;
  const int wm = (w & 1) * 64, wn = (w >> 1) * 64;
  const int row0 = by * 128;
  const int n0 = bx * 128;

  const int srow = (w << 5) + (lane >> 3);
  // swizzled source chunk: lane stores global chunk (lane&7)^(row&7); row&7 == lane>>3
  const int sswz = (((lane & 7) ^ (lane >> 3)) << 3);

  f32x4 acc[4][4] = {};

  for (int kt = 0; kt < KT; ++kt) {
    const int kbase = kt * 64;
    const unsigned short* Asrc = (kbase < K1) ? A1 : A2;
    const int kA = (kbase < K1) ? kbase : (kbase - K1);
    const int lda = (kbase < K1) ? K1 : K2;
#pragma unroll
    for (int q = 0; q < 4; ++q) {
      int rA = srow + q * 8;
      int rowg = row0 + rA;
      if (rowg >= nrows) rowg = nrows - 1;
      gload_lds16(Asrc + (size_t)rowg * lda + kA + sswz,
                  sA + ((w << 5) + q * 8) * 64);
      gload_lds16(Bt + (size_t)(n0 + rA) * KTOT + kbase + sswz,
                  sB + ((w << 5) + q * 8) * 64);
    }
    __syncthreads();
#pragma unroll
    for (int kk = 0; kk < 2; ++kk) {
      // fragment rows have row&7 == lane&7; chunk base = kk*4 + (lane>>4)
      const int ko_swz = (((kk * 4 + (lane >> 4)) ^ (lane & 7)) << 3);
      short8 a[4], b[4];
#pragma unroll
      for (int mi = 0; mi < 4; ++mi)
        a[mi] = *reinterpret_cast<const short8*>(
            &sA[(wm + mi * 16 + (lane & 15)) * 64 + ko_swz]);
#pragma unroll
      for (int ni = 0; ni < 4; ++ni)
        b[ni] = *reinterpret_cast<const short8*>(
            &sB[(wn + ni * 16 + (lane & 15)) * 64 + ko_swz]);
#pragma unroll
      for (int mi = 0; mi < 4; ++mi)
#pragma unroll
        for (int ni = 0; ni < 4; ++ni)
          acc[mi][ni] = __builtin_amdgcn_mfma_f32_16x16x32_bf16(a[mi], b[ni], acc[mi][ni], 0, 0, 0);
    }
    __syncthreads();
  }

  float* Co = (float*)smem;
#pragma unroll
  for (int h = 0; h < 2; ++h) {
    __syncthreads();
    if ((w >> 1) == h) {
#pragma unroll
      for (int mi = 0; mi < 4; ++mi)
#pragma unroll
        for (int ni = 0; ni < 4; ++ni) {
          int col = ni * 16 + (lane & 15);
          int rowb = wm + mi * 16 + (lane >> 4) * 4;
#pragma unroll
          for (int j = 0; j < 4; ++j) Co[(rowb + j) * 64 + col] = acc[mi][ni][j];
        }
    }
    __syncthreads();
    int sr = t >> 1, cb = (t & 1) * 32;
    int r = row0 + sr;
    if (r < nrows) {
      float v[32];
#pragma unroll
      for (int i = 0; i < 32; ++i) {
        v[i] = Co[sr * 64 + cb + i] + bias[n0 + h * 64 + cb + i];
        if (RELU) v[i] = fmaxf(v[i], 0.f);
      }
      if (OUT_BF16) {
        unsigned short* dst = (unsigned short*)outv + (size_t)r * ldo + n0 + h * 64 + cb;
#pragma unroll
        for (int q = 0; q < 4; ++q) {
          ushort8 o;
#pragma unroll
          for (int i = 0; i < 8; ++i) o[i] = f2bf(v[q * 8 + i]);
          *reinterpret_cast<ushort8*>(dst + q * 8) = o;
        }
      } else {
        float* dst = (float*)outv + (size_t)r * ldo + n0 + h * 64 + cb;
#pragma unroll
        for (int q = 0; q < 8; ++q) {
          float4 o = make_float4(v[4 * q], v[4 * q + 1], v[4 * q + 2], v[4 * q + 3]);
          *reinterpret_cast<float4*>(dst + 4 * q) = o;
        }
      }
    }
  }
}

template <int K1, int K2, bool RELU, bool OUT_BF16>
__global__ __launch_bounds__(256) void gemm_gl(
    const unsigned short* __restrict__ A1, const unsigned short* __restrict__ A2,
    const unsigned short* __restrict__ Bt, const float* __restrict__ bias,
    void* __restrict__ outv, int ldo, int nrows) {
  __shared__ char smem[32768];
  gemm_body<K1, K2, RELU, OUT_BF16>(blockIdx.x, blockIdx.y, A1, A2, Bt, bias, outv,
                                    ldo, nrows, smem);
}

// ---------------- tail GEMM K=512 + agg adds + fused BN partial stats ----------------
__global__ __launch_bounds__(256) void gemm_tail512(
    const unsigned short* __restrict__ A0, const unsigned short* __restrict__ A1,
    const unsigned short* __restrict__ Bt, const float* __restrict__ bias,
    const unsigned short* __restrict__ aYL, const unsigned short* __restrict__ aYG,
    float* __restrict__ outv, float* __restrict__ bnsums, int nrows) {
  constexpr int KTOT = 512;
  constexpr int KT = 8;
  __shared__ char smem[32768];
  __shared__ float psum[4][64], psum2[4][64];
  unsigned short* sA = (unsigned short*)smem;
  unsigned short* sB = sA + 8192;

  const int t = threadIdx.x;
  const int lane = t & 63;
  const int w = t >> 6;
  const int wm = (w & 1) * 64, wn = (w >> 1) * 64;
  const int row0 = blockIdx.y * 128;

  const int srow = (w << 5) + (lane >> 3);
  const int sswz = (((lane & 7) ^ (lane >> 3)) << 3);

  f32x4 acc[4][4] = {};

  for (int kt = 0; kt < KT; ++kt) {
    const unsigned short* Asrc = (kt < 4) ? A0 : A1;
    const int kA = (kt & 3) * 64;
#pragma unroll
    for (int q = 0; q < 4; ++q) {
      int rA = srow + q * 8;
      int rowg = row0 + rA;
      if (rowg >= nrows) rowg = nrows - 1;
      gload_lds16(Asrc + (size_t)rowg * 256 + kA + sswz,
                  sA + ((w << 5) + q * 8) * 64);
      gload_lds16(Bt + (size_t)rA * KTOT + kt * 64 + sswz,
                  sB + ((w << 5) + q * 8) * 64);
    }
    __syncthreads();
#pragma unroll
    for (int kk = 0; kk < 2; ++kk) {
      const int ko_swz = (((kk * 4 + (lane >> 4)) ^ (lane & 7)) << 3);
      short8 a[4], b[4];
#pragma unroll
      for (int mi = 0; mi < 4; ++mi)
        a[mi] = *reinterpret_cast<const short8*>(
            &sA[(wm + mi * 16 + (lane & 15)) * 64 + ko_swz]);
#pragma unroll
      for (int ni = 0; ni < 4; ++ni)
        b[ni] = *reinterpret_cast<const short8*>(
            &sB[(wn + ni * 16 + (lane & 15)) * 64 + ko_swz]);
#pragma unroll
      for (int mi = 0; mi < 4; ++mi)
#pragma unroll
        for (int ni = 0; ni < 4; ++ni)
          acc[mi][ni] = __builtin_amdgcn_mfma_f32_16x16x32_bf16(a[mi], b[ni], acc[mi][ni], 0, 0, 0);
    }
    __syncthreads();
  }

  float* Co = (float*)smem;
#pragma unroll
  for (int h = 0; h < 2; ++h) {
    __syncthreads();
    if ((w >> 1) == h) {
#pragma unroll
      for (int mi = 0; mi < 4; ++mi)
#pragma unroll
        for (int ni = 0; ni < 4; ++ni) {
          int col = ni * 16 + (lane & 15);
          int rowb = wm + mi * 16 + (lane >> 4) * 4;
#pragma unroll
          for (int j = 0; j < 4; ++j) Co[(rowb + j) * 64 + col] = acc[mi][ni][j];
        }
    }
    __syncthreads();
    int sr = t >> 1, cb = (t & 1) * 32;
    int r = row0 + sr;
    if (r < nrows) {
      float* dst = outv + (size_t)r * MLPH + h * 64 + cb;
#pragma unroll
      for (int q = 0; q < 4; ++q) {
        ushort8 ya = *reinterpret_cast<const ushort8*>(&aYL[(size_t)r * MLPH + h * 64 + cb + q * 8]);
        ushort8 yb = *reinterpret_cast<const ushort8*>(&aYG[(size_t)r * MLPH + h * 64 + cb + q * 8]);
        float v[8];
#pragma unroll
        for (int i = 0; i < 8; ++i) {
          v[i] = Co[sr * 64 + cb + q * 8 + i] + bf2f(ya[i]) + bf2f(yb[i]) +
                 bias[h * 64 + cb + q * 8 + i];
          Co[sr * 64 + cb + q * 8 + i] = v[i];
        }
        *reinterpret_cast<float4*>(dst + q * 8) = make_float4(v[0], v[1], v[2], v[3]);
        *reinterpret_cast<float4*>(dst + q * 8 + 4) = make_float4(v[4], v[5], v[6], v[7]);
      }
    }
    __syncthreads();
    {
      int c = t & 63, rq = t >> 6;
      float s = 0.f, s2 = 0.f;
      int rbeg = rq * 32;
      for (int rr = rbeg; rr < rbeg + 32; ++rr) {
        if (row0 + rr < nrows) {
          float v = Co[rr * 64 + c];
          s += v;
          s2 += v * v;
        }
      }
      psum[rq][c] = s;
      psum2[rq][c] = s2;
    }
    __syncthreads();
    if (t < 64) {
      float s = psum[0][t] + psum[1][t] + psum[2][t] + psum[3][t];
      float s2 = psum2[0][t] + psum2[1][t] + psum2[2][t] + psum2[3][t];
      atomicAdd(&bnsums[h * 64 + t], s);
      atomicAdd(&bnsums[128 + h * 64 + t], s2);
    }
    __syncthreads();
  }
}

// ---------------- BN finalize ----------------
__global__ __launch_bounds__(128) void bn_finalize_kernel(float* __restrict__ stats,
                                                          const float* __restrict__ gamma,
                                                          const float* __restrict__ beta) {
  int c = threadIdx.x;
  float mu = stats[c] * (1.0f / NN);
  float var = stats[128 + c] * (1.0f / NN) - mu * mu;
  var = fmaxf(var, 0.f);
  float sc = gamma[c] * rsqrtf(var + BN_EPS);
  stats[256 + c] = sc;
  stats[384 + c] = beta[c] - mu * sc;
}

// ---------------- final head GEMM with fused BN+ReLU on A-load (64x64) ----------------
template <int K1, bool RELU>
__global__ __launch_bounds__(256) void gemm_mfma_bn(
    const float* __restrict__ A1v, const unsigned short* __restrict__ Bt,
    const float* __restrict__ bias, const float* __restrict__ bnscale,
    const float* __restrict__ bnshift, float* __restrict__ outv, int ldo, int nrows) {
  constexpr int KT = K1 / 64;
  constexpr int LDT = 72;
  __shared__ char smem[2 * 64 * LDT * 2];
  unsigned short* As = (unsigned short*)smem;
  unsigned short* Bs = As + 64 * LDT;
  float* Co = (float*)smem;
  constexpr int LDC = 68;

  const int t = threadIdx.x;
  const int lane = t & 63;
  const int w = t >> 6;
  const int wm = (w & 1) * 32, wn = (w >> 1) * 32;
  const int row0 = blockIdx.y * 64;
  const int n0 = blockIdx.x * 64;

  const int sr = t >> 2;
  const int skc = (t & 3) * 16;
  int rg = row0 + sr;
  if (rg >= nrows) rg = nrows - 1;

  f32x4 acc[2][2] = {};

  for (int kt = 0; kt < KT; ++kt) {
    const int kbase = kt * 64;
    {
      const float* xb = A1v + (size_t)rg * K1 + kbase + skc;
      ushort8 o0, o1;
#pragma unroll
      for (int i = 0; i < 8; ++i) {
        float v = xb[i] * bnscale[kbase + skc + i] + bnshift[kbase + skc + i];
        o0[i] = f2bf(fmaxf(v, 0.f));
      }
#pragma unroll
      for (int i = 0; i < 8; ++i) {
        float v = xb[8 + i] * bnscale[kbase + skc + 8 + i] + bnshift[kbase + skc + 8 + i];
        o1[i] = f2bf(fmaxf(v, 0.f));
      }
      *reinterpret_cast<ushort8*>(&As[sr * LDT + skc]) = o0;
      *reinterpret_cast<ushort8*>(&As[sr * LDT + skc + 8]) = o1;
    }
    {
      const unsigned short* bb = Bt + (size_t)(n0 + sr) * K1 + kbase + skc;
      int4 p0 = *reinterpret_cast<const int4*>(bb);
      int4 p1 = *reinterpret_cast<const int4*>(bb + 8);
      *reinterpret_cast<int4*>(&Bs[sr * LDT + skc]) = p0;
      *reinterpret_cast<int4*>(&Bs[sr * LDT + skc + 8]) = p1;
    }
    __syncthreads();
#pragma unroll
    for (int kk = 0; kk < 2; ++kk) {
      const int ko = kk * 32 + (lane >> 4) * 8;
      short8 a0 = *reinterpret_cast<const short8*>(&As[(wm + (lane & 15)) * LDT + ko]);
      short8 a1 = *reinterpret_cast<const short8*>(&As[(wm + 16 + (lane & 15)) * LDT + ko]);
      short8 b0 = *reinterpret_cast<const short8*>(&Bs[(wn + (lane & 15)) * LDT + ko]);
      short8 b1 = *reinterpret_cast<const short8*>(&Bs[(wn + 16 + (lane & 15)) * LDT + ko]);
      acc[0][0] = __builtin_amdgcn_mfma_f32_16x16x32_bf16(a0, b0, acc[0][0], 0, 0, 0);
      acc[0][1] = __builtin_amdgcn_mfma_f32_16x16x32_bf16(a0, b1, acc[0][1], 0, 0, 0);
      acc[1][0] = __builtin_amdgcn_mfma_f32_16x16x32_bf16(a1, b0, acc[1][0], 0, 0, 0);
      acc[1][1] = __builtin_amdgcn_mfma_f32_16x16x32_bf16(a1, b1, acc[1][1], 0, 0, 0);
    }
    __syncthreads();
  }

#pragma unroll
  for (int mi = 0; mi < 2; ++mi)
#pragma unroll
    for (int ni = 0; ni < 2; ++ni) {
      int col = wn + ni * 16 + (lane & 15);
      int rowb = wm + mi * 16 + (lane >> 4) * 4;
#pragma unroll
      for (int j = 0; j < 4; ++j) Co[(rowb + j) * LDC + col] = acc[mi][ni][j];
    }
  __syncthreads();
  {
    int r = row0 + sr;
    if (r < nrows) {
      float v[16];
#pragma unroll
      for (int i = 0; i < 16; ++i) {
        v[i] = Co[sr * LDC + skc + i] + bias[n0 + skc + i];
        if (RELU) v[i] = fmaxf(v[i], 0.f);
      }
      float* dst = outv + (size_t)r * ldo + n0 + skc;
#pragma unroll
      for (int i = 0; i < 4; ++i) {
        float4 o = make_float4(v[4 * i], v[4 * i + 1], v[4 * i + 2], v[4 * i + 3]);
        *reinterpret_cast<float4*>(dst + 4 * i) = o;
      }
    }
  }
}

// ---------------- launch ----------------
extern "C" void kernel_launch(void* const* d_in, const int* in_sizes, int n_in,
                              void* d_out, int out_size, void* d_ws, size_t ws_size,
                              hipStream_t stream) {
  const float* feat = (const float*)d_in[0];
  const int* g_src = (const int*)d_in[1];
  const int* g_dst = (const int*)d_in[2];
  const int* k_src = (const int*)d_in[3];
  const int* k_dst = (const int*)d_in[4];
  const float* lb_0 = (const float*)d_in[7];
  const float* lb_1 = (const float*)d_in[10];
  const float* lb_2 = (const float*)d_in[13];
  const float* gb_0 = (const float*)d_in[16];
  const float* gb_1 = (const float*)d_in[19];
  const float* mlp_b1 = (const float*)d_in[21];
  const float* bn_gamma = (const float*)d_in[22];
  const float* bn_beta = (const float*)d_in[23];
  const float* mlp_b2 = (const float*)d_in[25];
  float* out = (float*)d_out;

  // workspace layout
  float* xf32 = (float*)d_ws;                         // N*128 f32
  int* cnt_g = (int*)(xf32 + (size_t)NN * 128);       // N
  int* cnt_k = cnt_g + NN;                            // N
  float* stats = (float*)(cnt_k + NN);                // 512
  int* gcnt = (int*)(stats + 512);                    // 16
  float* zbias = (float*)(gcnt + 16);                 // 128 (zeroed with block above)
  float* invg = zbias + 128;                          // N
  float* invk = invg + NN;                            // N
  int* off_g = (int*)(invk + NN);                     // N+4
  int* off_k = off_g + NN + 4;                        // N+4
  int* part = off_k + NN + 4;                         // 512
  unsigned* bkt_g = (unsigned*)(part + 512);          // 8*CAPG
  unsigned* bkt_k = bkt_g + 8 * CAPG;                 // 8*CAPK
  unsigned short* e16g = (unsigned short*)(bkt_k + 8 * CAPK);  // EG
  unsigned short* e16k = e16g + EG;                   // EK
  unsigned short* featbf = e16k + EK;                 // N*128
  unsigned short* wts = featbf + (size_t)NN * IN_F;   // 598016
  unsigned short* wf = wts + 598016;                  // 131072
  float* bfused = (float*)(wf + 131072);              // 128
  unsigned short* hL0 = (unsigned short*)(bfused + 128);  // N*256
  unsigned short* hG0 = hL0 + (size_t)NN * HF;        // N*256
  unsigned short* hL1 = hG0 + (size_t)NN * HF;        // N*256
  unsigned short* aggT = hL1 + (size_t)NN * HF;       // N*256
  unsigned short* aggFG = aggT + (size_t)NN * HF;     // N*128
  unsigned short* aggFK = aggFG + (size_t)NN * MLPH;  // N*128
  unsigned short* bfYL = aggFK + (size_t)NN * MLPH;   // N*128
  unsigned short* bfYG = bfYL + (size_t)NN * MLPH;    // N*128
  unsigned short* bfAYL = bfYG + (size_t)NN * MLPH;   // N*128
  unsigned short* bfAYG = bfAYL + (size_t)NN * MLPH;  // N*128

  const int wL0 = 0, wL1 = 65536, wG0 = 327680, wH2 = 589824;
  const int wfYL = 65536, wfYG = 98304;

  dim3 blk(256);
  const int NB = (NN + 255) / 256;        // 196
  const int MB = (NN + 127) / 128;        // 391
  const dim3 gridH(2, MB);                // 256-col out
  const dim3 gridM(1, MB);                // 128-col out
  const int agg128_blocks = (NN + 15) / 16;
  const int agg256_blocks = (NN + 7) / 8;
  const int BKB = (EK + 2047) / 2048;
  const int CC = 8;

  // zero cnt_g, cnt_k, stats, gcnt, zbias
  hipMemsetAsync(cnt_g, 0,
                 (size_t)(2 * NN) * sizeof(int) + 512 * sizeof(float) + 16 * sizeof(int) +
                     128 * sizeof(float),
                 stream);

  WPack p;
  p.d[0] = {(const float*)d_in[5], 128, 8, 0, 256, wL0};
  p.d[1] = {(const float*)d_in[6], 128, 8, 128, 256, wL0};
  p.d[2] = {(const float*)d_in[8], 256, 8, 0, 512, wL1};
  p.d[3] = {(const float*)d_in[9], 256, 8, 256, 512, wL1};
  p.d[4] = {(const float*)d_in[11], 256, 8, 0, 512, 196608};  // folded; layout keep
  p.d[5] = {(const float*)d_in[12], 256, 8, 256, 512, 196608};
  p.d[6] = {(const float*)d_in[14], 128, 8, 0, 256, wG0};
  p.d[7] = {(const float*)d_in[15], 128, 8, 128, 256, wG0};
  p.d[8] = {(const float*)d_in[17], 256, 8, 0, 512, 393216};  // folded
  p.d[9] = {(const float*)d_in[18], 256, 8, 256, 512, 393216};
  p.d[10] = {(const float*)d_in[20], 512, 7, 0, 512, 524288}; // folded
  p.d[11] = {(const float*)d_in[24], 128, 6, 0, 128, wH2};
  prep_kernel<<<3510, blk, 0, stream>>>(feat, featbf, p, wts);

  fuse_w_kernel<<<1025, 128, 0, stream>>>(
      (const float*)d_in[11], (const float*)d_in[12],
      (const float*)d_in[17], (const float*)d_in[18],
      (const float*)d_in[20], lb_2, gb_1, mlp_b1, wf, bfused);

  // ---- CSR build ----
  bucket_kernel<<<dim3(BKB, 2), blk, 0, stream>>>(g_src, g_dst, k_src, k_dst, gcnt, bkt_g, bkt_k);
  count_bucket<<<dim3(8, 2, CC), blk, 0, stream>>>(bkt_g, bkt_k, gcnt, cnt_g, cnt_k, CC);
  scan_partial2<<<dim3(NB, 2), blk, 0, stream>>>(cnt_g, cnt_k, part, NN);
  scan_block2<<<2, blk, 0, stream>>>(part, NB);
  scan_final2<<<dim3(NB, 2), blk, 0, stream>>>(cnt_g, cnt_k, part, off_g, off_k, invg, invk, NN);
  fill_sub<<<128, 1024, 0, stream>>>(bkt_g, bkt_k, gcnt, off_g, off_k, e16g, e16k);

  // ---- both feat aggregates (D=128, graphs g & k) in one dispatch ----
  csr_aggregate2<<<dim3(agg128_blocks, 2), blk, 0, stream>>>(
      featbf, off_g, e16g, invg, aggFG, featbf, off_k, e16k, invk, aggFK);
  // ---- l0 and g0 GEMMs ----
  gemm_gl<128, 128, true, true><<<gridH, blk, 0, stream>>>(
      featbf, aggFG, wts + wL0, lb_0, hL0, HF, NN);
  gemm_gl<128, 128, true, true><<<gridH, blk, 0, stream>>>(
      featbf, aggFK, wts + wG0, gb_0, hG0, HF, NN);
  // ---- l1 agg (D=256) + l1 GEMM ----
  csr_aggregate<8><<<agg256_blocks, blk, 0, stream>>>(hL0, off_g, e16g, invg, aggT);
  gemm_gl<256, 256, true, true><<<gridH, blk, 0, stream>>>(
      hL0, aggT, wts + wL1, lb_1, hL1, HF, NN);
  // ---- yl = hL1 @ Wf1, yg = hG0 @ Wf3 ----
  gemm_gl<256, 0, false, true><<<gridM, blk, 0, stream>>>(
      hL1, nullptr, wf + wfYL, zbias, bfYL, MLPH, NN);
  gemm_gl<256, 0, false, true><<<gridM, blk, 0, stream>>>(
      hG0, nullptr, wf + wfYG, zbias, bfYG, MLPH, NN);
  // ---- agg yl over g, yg over k (one dispatch) ----
  csr_aggregate2<<<dim3(agg128_blocks, 2), blk, 0, stream>>>(
      bfYL, off_g, e16g, invg, bfAYL, bfYG, off_k, e16k, invk, bfAYG);

  // ---- tail GEMM + fused BN stats ----
  gemm_tail512<<<gridM, blk, 0, stream>>>(hL1, hG0, wf, bfused, bfAYL, bfAYG, xf32, stats, NN);

  // ---- BN finalize + head GEMM2 ----
  bn_finalize_kernel<<<1, 128, 0, stream>>>(stats, bn_gamma, bn_beta);
  gemm_mfma_bn<128, false><<<dim3(1, (NN + 63) / 64), blk, 0, stream>>>(
      xf32, wts + wH2, mlp_b2, stats + 256, stats + 384, out, COUT, NN);
}